// Round 2
// baseline (325.775 us; speedup 1.0000x reference)
//
#include <hip/hip_runtime.h>
#include <math.h>

// Problem constants (N=512 Clements mesh, L=512 layers, fixed by reference).
#define NPORT  512
#define NLAYER 512
#define NPAIR  (NLAYER / 2)             // 256 even/odd layer pairs
#define ATTEN  0.9772372209558107f      // sqrt(10^(-0.2/10)) = 10^-0.01

// Coefficient table layout: per layer-PAIR p (layers 2p, 2p+1), 9 planes of
// 64 float4 (one per lane):
//   planes 0..3: even layer 2p,  lane t slot 4t+j   (ports 8t+2j, 8t+2j+1)
//   planes 4..7: odd  layer 2p+1, lane t slot 4t+j  (ports 8t+2j+1, 8t+2j+2)
//   plane  8   : odd layer left-crossing for lane t = slot 4t-1
//                (ports 8t-1, 8t)  — identity for lane 0
// Each float4 = {cos(th)*A, sin(th)*A, cos(ph), sin(ph)}; invalid slots get
// identity {1,0,1,0} (exact passthrough, matching role==2).
// Address: table[(p*9 + plane)*64 + lane] → lane-contiguous 16B = coalesced.

__global__ void coeff_kernel(const float* __restrict__ thetas,
                             const float* __restrict__ phis,
                             const int*   __restrict__ mzi_idx,
                             float4*      __restrict__ table) {
    int tid = blockIdx.x * blockDim.x + threadIdx.x;   // 0 .. NPAIR*9*64-1
    if (tid >= NPAIR * 9 * 64) return;
    int lane  = tid & 63;
    int plane = (tid >> 6) % 9;
    int p     = tid / (9 * 64);

    int layer, slot;
    bool valid;
    if (plane < 4) {                    // even layer
        layer = 2 * p;
        slot  = 4 * lane + plane;
        valid = true;                   // ports 2s,2s+1 always < 512
    } else if (plane < 8) {             // odd layer, local slots
        layer = 2 * p + 1;
        slot  = 4 * lane + (plane - 4);
        valid = (2 * slot + 2) < NPORT; // slot 255 -> ports 511/512 invalid
    } else {                            // odd layer, left-crossing
        layer = 2 * p + 1;
        slot  = 4 * lane - 1;
        valid = (lane > 0);
    }

    float4 c = make_float4(1.f, 0.f, 1.f, 0.f);
    if (valid) {
        int port_i = (layer & 1) ? (2 * slot + 1) : (2 * slot);
        int m  = mzi_idx[layer * NPORT + port_i];
        float th = thetas[m], ph = phis[m];
        c.x = cosf(th) * ATTEN;
        c.y = sinf(th) * ATTEN;
        c.z = cosf(ph);
        c.w = sinf(ph);
    }
    table[(size_t)(p * 9 + plane) * 64 + lane] = c;
}

// ---------------------------------------------------------------------------
// Mesh propagation. 256 threads = 4 waves per block; each wave owns one batch
// row (lane t holds ports 8t..8t+7 in registers). 256 blocks -> 1 block/CU,
// the 4 waves read identical coefficient addresses -> L1 serves 3/4 of the
// table traffic as long as they stay converged (periodic __syncthreads).
//
// Even layer: 4 lane-internal MZIs (no communication).
// Odd layer:  both shuffles issued up-front on OLD values (shfl_down of
// port0 for the right crossing, shfl_up of port7 for the left crossing),
// then 3 internal MZIs + both crossings computed locally — no serial
// shfl->compute->shfl chain.
//
// Coefficients prefetched 3 layer-pairs deep in explicit register buffers
// (4 buffers x 9 float4 = 144 VGPRs). __launch_bounds__(256,1): we only need
// 1 wave/EU, so let the allocator keep them live.
// ---------------------------------------------------------------------------
struct PairCoef {
    float4 e[4];   // even layer slots
    float4 o[5];   // odd layer slots + left-crossing
};

template <bool USE_TABLE>
__global__ __launch_bounds__(256, 1)
void mesh_kernel(const float*  __restrict__ x,
                 const float*  __restrict__ thetas,
                 const float*  __restrict__ phis,
                 const int*    __restrict__ mzi_idx,
                 const float4* __restrict__ table,
                 float*        __restrict__ out,
                 int B) {
    const int lane = threadIdx.x & 63;
    const int wid  = threadIdx.x >> 6;
    const int row  = blockIdx.x * 4 + wid;
    const bool live = row < B;

    // Load 8 consecutive real inputs -> complex state (im = 0).
    const float4* xr = (const float4*)(x + (size_t)(live ? row : 0) * NPORT + lane * 8);
    float4 xa = xr[0], xb = xr[1];
    float sr[8] = {xa.x, xa.y, xa.z, xa.w, xb.x, xb.y, xb.z, xb.w};
    float si[8] = {0.f, 0.f, 0.f, 0.f, 0.f, 0.f, 0.f, 0.f};

    auto loadPair = [&](int p, PairCoef& b) {
        if (USE_TABLE) {
            const float4* base = table + (size_t)p * 9 * 64 + lane;
#pragma unroll
            for (int j = 0; j < 4; ++j) b.e[j] = base[j * 64];
#pragma unroll
            for (int j = 0; j < 5; ++j) b.o[j] = base[(4 + j) * 64];
        } else {
            // Fallback: compute trig inline (only if ws too small for table).
#pragma unroll
            for (int j = 0; j < 4; ++j) {
                int m = mzi_idx[(2 * p) * NPORT + (8 * lane + 2 * j)];
                float th = thetas[m], ph = phis[m];
                b.e[j] = make_float4(cosf(th) * ATTEN, sinf(th) * ATTEN,
                                     cosf(ph), sinf(ph));
            }
#pragma unroll
            for (int j = 0; j < 4; ++j) {
                int s = 4 * lane + j;
                if (2 * s + 2 < NPORT) {
                    int m = mzi_idx[(2 * p + 1) * NPORT + (2 * s + 1)];
                    float th = thetas[m], ph = phis[m];
                    b.o[j] = make_float4(cosf(th) * ATTEN, sinf(th) * ATTEN,
                                         cosf(ph), sinf(ph));
                } else {
                    b.o[j] = make_float4(1.f, 0.f, 1.f, 0.f);
                }
            }
            if (lane > 0) {
                int m = mzi_idx[(2 * p + 1) * NPORT + (8 * lane - 1)];
                float th = thetas[m], ph = phis[m];
                b.o[4] = make_float4(cosf(th) * ATTEN, sinf(th) * ATTEN,
                                     cosf(ph), sinf(ph));
            } else {
                b.o[4] = make_float4(1.f, 0.f, 1.f, 0.f);
            }
        }
    };

    // One MZI, both ports lane-local. Upper gets the phase.
    auto mzi = [&](const float4 c, int p0, int p1) {
        float ct = c.x, st = c.y, er = c.z, ei = c.w;
        float ur = ct * sr[p0] + st * sr[p1];
        float ui = ct * si[p0] + st * si[p1];
        float lr = ct * sr[p1] - st * sr[p0];
        float li = ct * si[p1] - st * si[p0];
        sr[p0] = er * ur - ei * ui;
        si[p0] = er * ui + ei * ur;
        sr[p1] = lr;
        si[p1] = li;
    };

    auto computePair = [&](const PairCoef& b) {
        // ---- even layer: ports (2j, 2j+1), all local ----
#pragma unroll
        for (int j = 0; j < 4; ++j) mzi(b.e[j], 2 * j, 2 * j + 1);

        // ---- odd layer ----
        // Capture OLD boundary values first; both shuffles independent.
        float hr = __shfl_down(sr[0], 1);  // right neighbor's old port 8t+8
        float hi = __shfl_down(si[0], 1);
        float gr = __shfl_up(sr[7], 1);    // left neighbor's old port 8t-1
        float gi = __shfl_up(si[7], 1);
        // 3 internal MZIs: ports (2j+1, 2j+2), j=0..2
#pragma unroll
        for (int j = 0; j < 3; ++j) mzi(b.o[j], 2 * j + 1, 2 * j + 2);
        // Right crossing (upper = local port 7, lower = h). Keep upper.
        {
            float ct = b.o[3].x, st = b.o[3].y, er = b.o[3].z, ei = b.o[3].w;
            float ur = ct * sr[7] + st * hr;
            float ui = ct * si[7] + st * hi;
            sr[7] = er * ur - ei * ui;
            si[7] = er * ui + ei * ur;
        }
        // Left crossing (upper = g, lower = local port 0). Keep lower.
        // Lane 0: identity coeffs -> sr0 = 1*sr0 - 0*g (exact passthrough).
        {
            float ct = b.o[4].x, st = b.o[4].y;
            float lr = ct * sr[0] - st * gr;
            float li = ct * si[0] - st * gi;
            sr[0] = lr;
            si[0] = li;
        }
    };

    PairCoef b0, b1, b2, b3;
    loadPair(0, b0);
    loadPair(1, b1);
    loadPair(2, b2);

    for (int p = 0; p < NPAIR; p += 4) {
        // Barrier BEFORE fresh prefetches: outstanding loads are a full
        // compute-pair old (~done), so the vmcnt drain is cheap. Keeps the
        // block's 4 waves within the L1 window of the coeff stream.
        __syncthreads();
        int c3 = p + 3 < NPAIR ? p + 3 : NPAIR - 1;
        int c4 = p + 4 < NPAIR ? p + 4 : NPAIR - 1;
        int c5 = p + 5 < NPAIR ? p + 5 : NPAIR - 1;
        int c6 = p + 6 < NPAIR ? p + 6 : NPAIR - 1;
        loadPair(c3, b3);
        computePair(b0);
        loadPair(c4, b0);
        computePair(b1);
        loadPair(c5, b1);
        computePair(b2);
        loadPair(c6, b2);
        computePair(b3);
    }

    // Photodetection: |E|^2, vectorized store.
    if (live) {
        float4 o0 = make_float4(sr[0] * sr[0] + si[0] * si[0],
                                sr[1] * sr[1] + si[1] * si[1],
                                sr[2] * sr[2] + si[2] * si[2],
                                sr[3] * sr[3] + si[3] * si[3]);
        float4 o1 = make_float4(sr[4] * sr[4] + si[4] * si[4],
                                sr[5] * sr[5] + si[5] * si[5],
                                sr[6] * sr[6] + si[6] * si[6],
                                sr[7] * sr[7] + si[7] * si[7]);
        float4* op = (float4*)(out + (size_t)row * NPORT + lane * 8);
        op[0] = o0;
        op[1] = o1;
    }
}

// ---------------------------------------------------------------------------
// Inputs (setup_inputs order): x[B*N] f32, thetas[M] f32, phis[M] f32,
// partner[L*N] i32 (unused), mzi_idx[L*N] i32, role[L*N] i32 (unused).
// ---------------------------------------------------------------------------
extern "C" void kernel_launch(void* const* d_in, const int* in_sizes, int n_in,
                              void* d_out, int out_size, void* d_ws,
                              size_t ws_size, hipStream_t stream) {
    const float* x       = (const float*)d_in[0];
    const float* thetas  = (const float*)d_in[1];
    const float* phis    = (const float*)d_in[2];
    const int*   mzi_idx = (const int*)d_in[4];
    float*       out     = (float*)d_out;

    int B = in_sizes[0] / NPORT;
    int nblk = (B + 3) / 4;

    const size_t table_bytes = (size_t)NPAIR * 9 * 64 * sizeof(float4); // 2.25 MiB
    if (ws_size >= table_bytes) {
        float4* table = (float4*)d_ws;
        int nthreads = NPAIR * 9 * 64;
        coeff_kernel<<<(nthreads + 255) / 256, 256, 0, stream>>>(
            thetas, phis, mzi_idx, table);
        mesh_kernel<true><<<nblk, 256, 0, stream>>>(x, thetas, phis, mzi_idx,
                                                    table, out, B);
    } else {
        mesh_kernel<false><<<nblk, 256, 0, stream>>>(x, thetas, phis, mzi_idx,
                                                     nullptr, out, B);
    }
}

// Round 3
// 175.621 us; speedup vs baseline: 1.8550x; 1.8550x over previous
//
#include <hip/hip_runtime.h>
#include <math.h>

// Problem constants (N=512 Clements mesh, L=512 layers, fixed by reference).
#define NPORT  512
#define NLAYER 512
#define NPAIR  256                      // even/odd layer pairs
#define CHUNK  4                        // layer-pairs per LDS stage
#define NCHUNK (NPAIR / CHUNK)          // 64 chunks
#define PPL    8                        // coefficient planes per pair
#define PLANES (CHUNK * PPL)            // 32 planes per chunk (32 KB)
#define ATTEN  0.9772372209558107f      // sqrt(10^(-0.2/10))

// Async global->LDS DMA, 16B per lane: LDS dst = uniform base + lane*16.
__device__ __forceinline__ void load_lds16(const float4* g, void* l) {
    __builtin_amdgcn_global_load_lds(
        (const __attribute__((address_space(1))) void*)g,
        (__attribute__((address_space(3))) void*)l, 16, 0, 0);
}

// ---------------------------------------------------------------------------
// Coefficient table: per layer-pair p, 8 planes of 64 float4 (one per lane):
//   planes 0..3: even layer 2p,  lane t slot 4t+j (ports 8t+2j, 8t+2j+1)
//   planes 4..7: odd  layer 2p+1, lane t slot 4t+j (ports 8t+2j+1, 8t+2j+2)
// float4 = {cos(th)*A, sin(th)*A, cos(ph), sin(ph)}; invalid slot (odd,255)
// = identity {1,0,1,0}. The odd-layer LEFT-crossing coefficient for lane t
// (slot 4t-1) is NOT stored: it equals lane t-1's plane-7 value (shfl_up).
// Address table[(p*8+plane)*64 + lane] -> plane = 1 KB contiguous, matching
// global_load_lds's lane*16 scatter exactly.
// ---------------------------------------------------------------------------
__global__ void coeff_kernel(const float* __restrict__ thetas,
                             const float* __restrict__ phis,
                             const int*   __restrict__ mzi_idx,
                             float4*      __restrict__ table) {
    int tid = blockIdx.x * blockDim.x + threadIdx.x;   // 0 .. NPAIR*8*64-1
    if (tid >= NPAIR * PPL * 64) return;
    int lane  = tid & 63;
    int plane = (tid >> 6) & 7;
    int p     = tid >> 9;

    int layer, slot, port_i;
    bool valid;
    if (plane < 4) {                    // even layer
        layer  = 2 * p;
        slot   = 4 * lane + plane;
        port_i = 2 * slot;
        valid  = true;
    } else {                            // odd layer local slots
        layer  = 2 * p + 1;
        slot   = 4 * lane + (plane - 4);
        port_i = 2 * slot + 1;
        valid  = (2 * slot + 2) < NPORT;   // slot 255 -> ports 511/512
    }

    float4 c = make_float4(1.f, 0.f, 1.f, 0.f);
    if (valid) {
        int m  = mzi_idx[layer * NPORT + port_i];
        float th = thetas[m], ph = phis[m];
        c.x = cosf(th) * ATTEN;
        c.y = sinf(th) * ATTEN;
        c.z = cosf(ph);
        c.w = sinf(ph);
    }
    table[(size_t)(p * PPL + plane) * 64 + lane] = c;
}

// ---------------------------------------------------------------------------
// Mesh propagation. 256 threads = 4 waves/block, one batch row per wave;
// lane t holds ports 8t..8t+7 (complex) in registers.
// Coefficients pipeline: chunk of 4 layer-pairs staged in LDS via
// global_load_lds (each wave DMAs 8 planes), double-buffered across two
// DISTINCT __shared__ arrays; consumption via ds_read_b128. One
// __syncthreads per chunk drains the DMA (issued one full chunk of compute
// earlier -> near-zero stall).
// ---------------------------------------------------------------------------
struct PairCoef {
    float4 e[4];   // even-layer slots
    float4 o[4];   // odd-layer local slots
};

__global__ __launch_bounds__(256, 1)
void mesh_kernel(const float*  __restrict__ x,
                 const float4* __restrict__ table,
                 float*        __restrict__ out,
                 int B) {
    __shared__ float4 bufA[PLANES][64];   // 32 KB
    __shared__ float4 bufB[PLANES][64];   // 32 KB

    const int lane = threadIdx.x & 63;
    const int wid  = threadIdx.x >> 6;
    const int row  = blockIdx.x * 4 + wid;
    const bool live = row < B;

    // Load 8 consecutive real inputs -> complex state (im = 0).
    const float4* xr =
        (const float4*)(x + (size_t)(live ? row : 0) * NPORT) + lane * 2;
    float4 xa = xr[0], xb = xr[1];
    float sr[8] = {xa.x, xa.y, xa.z, xa.w, xb.x, xb.y, xb.z, xb.w};
    float si[8] = {0.f, 0.f, 0.f, 0.f, 0.f, 0.f, 0.f, 0.f};

    // DMA chunk c's 32 planes into buf; wave w takes planes 8w..8w+7.
    auto stage = [&](int c, float4 (*buf)[64]) {
        const float4* g = table + (size_t)c * (PLANES * 64) + lane;
#pragma unroll
        for (int k = 0; k < PPL; ++k) {
            int pl = wid * PPL + k;
            load_lds16(g + pl * 64, (void*)&buf[pl][0]);
        }
    };

    // One MZI, both ports lane-local; upper port gets the phase.
    auto mzi = [&](const float4 c, int p0, int p1) {
        float ct = c.x, st = c.y, er = c.z, ei = c.w;
        float ur = ct * sr[p0] + st * sr[p1];
        float ui = ct * si[p0] + st * si[p1];
        float lr = ct * sr[p1] - st * sr[p0];
        float li = ct * si[p1] - st * si[p0];
        sr[p0] = er * ur - ei * ui;
        si[p0] = er * ui + ei * ur;
        sr[p1] = lr;
        si[p1] = li;
    };

    auto computePair = [&](const PairCoef& b) {
        // Even layer: ports (2j, 2j+1), all lane-local.
#pragma unroll
        for (int j = 0; j < 4; ++j) mzi(b.e[j], 2 * j, 2 * j + 1);

        // Odd layer. All 6 shuffles issued up-front on OLD values.
        float hr = __shfl_down(sr[0], 1);     // right neighbor's port 8t+8
        float hi = __shfl_down(si[0], 1);
        float gr = __shfl_up(sr[7], 1);       // left neighbor's port 8t-1
        float gi = __shfl_up(si[7], 1);
        float lc = __shfl_up(b.o[3].x, 1);    // left-crossing ct (slot 4t-1)
        float ls = __shfl_up(b.o[3].y, 1);    // left-crossing st
        float ct4 = (lane > 0) ? lc : 1.f;    // lane 0: port 0 passthrough
        float st4 = (lane > 0) ? ls : 0.f;

        // 3 internal MZIs: ports (2j+1, 2j+2).
#pragma unroll
        for (int j = 0; j < 3; ++j) mzi(b.o[j], 2 * j + 1, 2 * j + 2);

        // Right crossing (upper = local port 7, lower = h): keep upper+phase.
        {
            float ct = b.o[3].x, st = b.o[3].y, er = b.o[3].z, ei = b.o[3].w;
            float ur = ct * sr[7] + st * hr;
            float ui = ct * si[7] + st * hi;
            sr[7] = er * ur - ei * ui;
            si[7] = er * ui + ei * ur;
        }
        // Left crossing (upper = g, lower = local port 0): keep lower.
        {
            float lr = ct4 * sr[0] - st4 * gr;
            float li = ct4 * si[0] - st4 * gi;
            sr[0] = lr;
            si[0] = li;
        }
    };

    auto readPair = [&](const float4 (*buf)[64], int pp) {
        PairCoef b;
#pragma unroll
        for (int j = 0; j < 4; ++j) b.e[j] = buf[pp * PPL + j][lane];
#pragma unroll
        for (int j = 0; j < 4; ++j) b.o[j] = buf[pp * PPL + 4 + j][lane];
        return b;
    };

    auto computeChunk = [&](const float4 (*buf)[64]) {
        PairCoef A = readPair(buf, 0);
#pragma unroll
        for (int pp = 0; pp < CHUNK; ++pp) {
            PairCoef Bn;
            if (pp + 1 < CHUNK) Bn = readPair(buf, pp + 1);  // 1-deep pipeline
            computePair(A);
            if (pp + 1 < CHUNK) A = Bn;
        }
    };

    stage(0, bufA);
    __syncthreads();

#pragma unroll 1
    for (int c = 0; c < NCHUNK; c += 2) {
        if (c + 1 < NCHUNK) stage(c + 1, bufB);
        computeChunk(bufA);
        __syncthreads();
        if (c + 2 < NCHUNK) stage(c + 2, bufA);
        computeChunk(bufB);
        __syncthreads();
    }

    // Photodetection: |E|^2, vectorized store.
    if (live) {
        float4 o0 = make_float4(sr[0] * sr[0] + si[0] * si[0],
                                sr[1] * sr[1] + si[1] * si[1],
                                sr[2] * sr[2] + si[2] * si[2],
                                sr[3] * sr[3] + si[3] * si[3]);
        float4 o1 = make_float4(sr[4] * sr[4] + si[4] * si[4],
                                sr[5] * sr[5] + si[5] * si[5],
                                sr[6] * sr[6] + si[6] * si[6],
                                sr[7] * sr[7] + si[7] * si[7]);
        float4* op = (float4*)(out + (size_t)row * NPORT) + lane * 2;
        op[0] = o0;
        op[1] = o1;
    }
}

// ---------------------------------------------------------------------------
// Fallback (ws too small for the table): trig inline, slow but correct.
// ---------------------------------------------------------------------------
__global__ __launch_bounds__(64)
void mesh_fallback(const float* __restrict__ x,
                   const float* __restrict__ thetas,
                   const float* __restrict__ phis,
                   const int*   __restrict__ mzi_idx,
                   float*       __restrict__ out) {
    const int lane = threadIdx.x;
    const int row  = blockIdx.x;

    const float4* xr = (const float4*)(x + (size_t)row * NPORT) + lane * 2;
    float4 xa = xr[0], xb = xr[1];
    float sr[8] = {xa.x, xa.y, xa.z, xa.w, xb.x, xb.y, xb.z, xb.w};
    float si[8] = {0.f, 0.f, 0.f, 0.f, 0.f, 0.f, 0.f, 0.f};

    auto mzi = [&](float ct, float st, float er, float ei, int p0, int p1) {
        float ur = ct * sr[p0] + st * sr[p1];
        float ui = ct * si[p0] + st * si[p1];
        float lr = ct * sr[p1] - st * sr[p0];
        float li = ct * si[p1] - st * si[p0];
        sr[p0] = er * ur - ei * ui;
        si[p0] = er * ui + ei * ur;
        sr[p1] = lr;
        si[p1] = li;
    };

    for (int l = 0; l < NLAYER; ++l) {
        if ((l & 1) == 0) {
#pragma unroll
            for (int j = 0; j < 4; ++j) {
                int m = mzi_idx[l * NPORT + (8 * lane + 2 * j)];
                float th = thetas[m], ph = phis[m];
                mzi(cosf(th) * ATTEN, sinf(th) * ATTEN, cosf(ph), sinf(ph),
                    2 * j, 2 * j + 1);
            }
        } else {
            float hr = __shfl_down(sr[0], 1);
            float hi = __shfl_down(si[0], 1);
#pragma unroll
            for (int j = 0; j < 3; ++j) {
                int m = mzi_idx[l * NPORT + (8 * lane + 2 * j + 1)];
                float th = thetas[m], ph = phis[m];
                mzi(cosf(th) * ATTEN, sinf(th) * ATTEN, cosf(ph), sinf(ph),
                    2 * j + 1, 2 * j + 2);
            }
            float ct = 1.f, st = 0.f, er = 1.f, ei = 0.f;
            if (lane < 63) {
                int m = mzi_idx[l * NPORT + (8 * lane + 7)];
                float th = thetas[m], ph = phis[m];
                ct = cosf(th) * ATTEN; st = sinf(th) * ATTEN;
                er = cosf(ph); ei = sinf(ph);
            }
            float ur = ct * sr[7] + st * hr;
            float ui = ct * si[7] + st * hi;
            float lr = ct * hr - st * sr[7];
            float li = ct * hi - st * si[7];
            sr[7] = er * ur - ei * ui;
            si[7] = er * ui + ei * ur;
            float rlr = __shfl_up(lr, 1);
            float rli = __shfl_up(li, 1);
            sr[0] = (lane > 0) ? rlr : sr[0];
            si[0] = (lane > 0) ? rli : si[0];
        }
    }

    float4 o0 = make_float4(sr[0] * sr[0] + si[0] * si[0],
                            sr[1] * sr[1] + si[1] * si[1],
                            sr[2] * sr[2] + si[2] * si[2],
                            sr[3] * sr[3] + si[3] * si[3]);
    float4 o1 = make_float4(sr[4] * sr[4] + si[4] * si[4],
                            sr[5] * sr[5] + si[5] * si[5],
                            sr[6] * sr[6] + si[6] * si[6],
                            sr[7] * sr[7] + si[7] * si[7]);
    float4* op = (float4*)(out + (size_t)row * NPORT) + lane * 2;
    op[0] = o0;
    op[1] = o1;
}

// ---------------------------------------------------------------------------
// Inputs (setup_inputs order): x[B*N] f32, thetas[M] f32, phis[M] f32,
// partner[L*N] i32 (unused), mzi_idx[L*N] i32, role[L*N] i32 (unused).
// ---------------------------------------------------------------------------
extern "C" void kernel_launch(void* const* d_in, const int* in_sizes, int n_in,
                              void* d_out, int out_size, void* d_ws,
                              size_t ws_size, hipStream_t stream) {
    const float* x       = (const float*)d_in[0];
    const float* thetas  = (const float*)d_in[1];
    const float* phis    = (const float*)d_in[2];
    const int*   mzi_idx = (const int*)d_in[4];
    float*       out     = (float*)d_out;

    int B = in_sizes[0] / NPORT;

    const size_t table_bytes = (size_t)NPAIR * PPL * 64 * sizeof(float4); // 2 MiB
    if (ws_size >= table_bytes) {
        float4* table = (float4*)d_ws;
        int nthreads = NPAIR * PPL * 64;
        coeff_kernel<<<(nthreads + 255) / 256, 256, 0, stream>>>(
            thetas, phis, mzi_idx, table);
        int nblk = (B + 3) / 4;
        mesh_kernel<<<nblk, 256, 0, stream>>>(x, table, out, B);
    } else {
        mesh_fallback<<<B, 64, 0, stream>>>(x, thetas, phis, mzi_idx, out);
    }
}